// Round 19
// baseline (223.175 us; speedup 1.0000x reference)
//
#include <hip/hip_runtime.h>

// MaxUnpooling2D scatter-add. out flat index o = (b<<22) | (mask & ~63) | c.
// B=16 H=W=128 C=64 OH=OW=256.  N=2^24 inputs, OUT_N=2^26 outputs.
//
// R1/R2: global fp32 atomics (any scope) -> memory-side RMW, 32B/op.
// R3-R7: bin(counting sort)+apply(LDS accumulate), packed u32 queue -> 160us.
// R8/R10/R16/R18 structural fixes NULL; R14 -10; R17 -30. Best: R13 @156.6us.
// R12/R15: stores 36us @7TB/s marginal, loads ~11us, VALU 2% -> apply's ~65us
//   "rest" is stalled on an uncounted pipe; prime suspect = DS pipe (16.7M
//   random ds_add_f32 atomics + 64KB zero/read sweeps).
// R19: MEASUREMENT. apply<false> (no ds_adds, loads kept live via asm) runs
//   BEFORE apply<true> (full) -> output bit-identical; dur = 156.6 + (101 -
//   accum_cost). 218-233 => DS-atomic-bound (fix bank layout); ~250 => plateau.

typedef float  f32x4 __attribute__((ext_vector_type(4)));
typedef int    i32x4 __attribute__((ext_vector_type(4)));
typedef unsigned int u32x4 __attribute__((ext_vector_type(4)));

constexpr long N = 1L << 24;
constexpr long OUT_N = 1L << 26;
constexpr int IN_B_SHIFT = 20;          // elements per input batch = 2^20

constexpr int REG_SHIFT = 14;           // 2^14 floats (64KB out) per region
constexpr int RPB = 256;                // regions per batch
constexpr int R = 4096;                 // total regions
constexpr unsigned CAP = 4608;          // mean 4096 + 8 sigma
constexpr int CHUNK = 8192;             // input elements per bin block
constexpr int NCHUNK = (int)(N / CHUNK);        // 2048
constexpr int BIN_T = 512;              // bin threads
constexpr int APL_T = 1024;             // apply threads
constexpr int APL_BLOCKS = 512;         // 2 blocks/CU
constexpr int NR = R / APL_BLOCKS;      // 8 regions per apply block
constexpr int VPT = CHUNK / 4 / BIN_T;          // 4 vec4 per thread

// ws layout: u32 cursor[R] | u32 pack[R*CAP]
constexpr size_t PACK_OFF = 65536;
constexpr size_t WS_NEED = PACK_OFF + (size_t)R * CAP * 4;   // ~75.6 MB

__device__ __forceinline__ unsigned umin_(unsigned a, unsigned b) { return a < b ? a : b; }

// off14 in [0,16384), val as bf16 (RNE) in low 16 bits.
__device__ __forceinline__ unsigned pack_entry(unsigned off14, float v) {
    unsigned bu = __float_as_uint(v);
    unsigned b16 = (bu + 0x7FFFu + ((bu >> 16) & 1u)) >> 16;
    return (off14 << 16) | b16;
}

// ---------------- fallback (round-1) kernel ----------------
__global__ __launch_bounds__(256) void unpool_scatter_kernel(
    const float4* __restrict__ upd, const int4* __restrict__ mask,
    float* __restrict__ out, int nvec) {
    int i = blockIdx.x * blockDim.x + threadIdx.x;
    if (i >= nvec) return;
    float4 u = upd[i];
    int4 m = mask[i];
    int flat = i << 2;
    int b = flat >> IN_B_SHIFT;
    float* obase = out + ((long)b << 22);
    int c0 = flat & 63;
    atomicAdd(obase + ((m.x & ~63) | (c0 + 0)), u.x);
    atomicAdd(obase + ((m.y & ~63) | (c0 + 1)), u.y);
    atomicAdd(obase + ((m.z & ~63) | (c0 + 2)), u.z);
    atomicAdd(obase + ((m.w & ~63) | (c0 + 3)), u.w);
}

// -------- phase A: block-local counting sort, then coalesced queue append --------
__global__ __launch_bounds__(BIN_T, 8) void bin_kernel(
    const f32x4* __restrict__ upd, const i32x4* __restrict__ maskv,
    unsigned* __restrict__ cursor, unsigned* __restrict__ pack) {
    __shared__ unsigned       s_pack[CHUNK];    // 32 KB: packed entries (sorted)
    __shared__ unsigned char  s_reg[CHUNK];     //  8 KB: region within batch
    __shared__ unsigned s_cnt[RPB];             // histogram -> scatter cursor
    __shared__ unsigned s_lbase[RPB];           // local exclusive prefix
    __shared__ unsigned s_gbase[RPB];           // clamped global queue base
    __shared__ unsigned s_wsum[4];

    int t = threadIdx.x;
    int blk = blockIdx.x;
    if (t < RPB) s_cnt[t] = 0;
    __syncthreads();

    int vbase = blk * (CHUNK / 4);              // 2048 vec4 per block
    unsigned b = (unsigned)blk >> 7;            // 128 blocks per batch
    unsigned rbase = b << 8;

    unsigned pk[VPT][4];
    unsigned r3p[VPT];                          // 4x 8-bit region ids per vec4
#pragma unroll
    for (int g = 0; g < VPT; ++g) {
        i32x4 m = __builtin_nontemporal_load(&maskv[vbase + g * BIN_T + t]);
        f32x4 u = __builtin_nontemporal_load(&upd[vbase + g * BIN_T + t]);
        unsigned ch0 = ((unsigned)((vbase + g * BIN_T + t) << 2)) & 63u;
        unsigned rp = 0;
#define HIST(MJ, VJ, J)                                                      \
        {                                                                    \
            unsigned mm = (unsigned)(MJ), r3 = mm >> REG_SHIFT;              \
            atomicAdd(&s_cnt[r3], 1u);                                       \
            pk[g][J] = pack_entry((mm & 0x3FC0u) | (ch0 + (J)), (VJ));       \
            rp |= r3 << (8 * (J));                                           \
        }
        HIST(m.x, u.x, 0)
        HIST(m.y, u.y, 1)
        HIST(m.z, u.z, 2)
        HIST(m.w, u.w, 3)
#undef HIST
        r3p[g] = rp;
    }
    __syncthreads();

    if (t < RPB) {  // exclusive prefix scan over 256 counts + global reservation
        unsigned lane = t & 63u, wave = (unsigned)t >> 6;
        unsigned c = s_cnt[t];
        unsigned x = c;
#pragma unroll
        for (int d = 1; d < 64; d <<= 1) {
            unsigned y = __shfl_up(x, d);
            if (lane >= (unsigned)d) x += y;
        }
        if (lane == 63) s_wsum[wave] = x;
        __syncthreads();
        unsigned woff = 0;
        for (unsigned w = 0; w < wave; ++w) woff += s_wsum[w];
        unsigned excl = woff + x - c;
        s_lbase[t] = excl;
        unsigned raw = atomicAdd(&cursor[rbase + (unsigned)t], c);
        s_gbase[t] = umin_(raw, CAP);
        s_cnt[t] = excl;                        // becomes the scatter cursor
    } else {
        __syncthreads();
    }
    __syncthreads();

    // Scatter into LDS in region-sorted order.
#pragma unroll
    for (int g = 0; g < VPT; ++g) {
#pragma unroll
        for (int j = 0; j < 4; ++j) {
            unsigned r3 = (r3p[g] >> (8 * j)) & 255u;
            unsigned s = atomicAdd(&s_cnt[r3], 1u);
            s_pack[s] = pk[g][j];
            s_reg[s] = (unsigned char)r3;
        }
    }
    __syncthreads();

    // Coalesced writeback: consecutive i -> consecutive global queue slots
    // within each region run.
    for (int i = t; i < CHUNK; i += BIN_T) {
        unsigned r3 = s_reg[i];
        unsigned idx = s_gbase[r3] + ((unsigned)i - s_lbase[r3]);
        if (idx < CAP)
            pack[(size_t)(rbase + r3) * CAP + idx] = s_pack[i];
    }
}

// -------- phase B: R13 structure, templated on ACCUM for the ablation --------
struct QS { u32x4 a, b; unsigned tail; unsigned nv; unsigned len; };

__device__ __forceinline__ QS load_q(const unsigned* __restrict__ cursor,
                                     const unsigned* __restrict__ pack,
                                     unsigned r, unsigned t) {
    QS q;
    q.len = umin_(cursor[r], CAP);
    q.nv = q.len >> 2;
    size_t qb = (size_t)r * CAP;
    const u32x4* p4 = (const u32x4*)(pack + qb);    // CAP%4==0 -> 16B aligned
    q.a = (t < q.nv) ? __builtin_nontemporal_load(&p4[t]) : (u32x4)(0u);
    q.b = (t + APL_T < q.nv) ? __builtin_nontemporal_load(&p4[t + APL_T]) : (u32x4)(0u);
    unsigned ti = (q.nv << 2) + t;
    q.tail = (ti < q.len) ? pack[qb + ti] : 0u;
    return q;
}

template <bool ACCUM>
__global__ __launch_bounds__(APL_T, 2) void apply_kernel(
    const unsigned* __restrict__ cursor, const unsigned* __restrict__ pack,
    float* __restrict__ out) {
    __shared__ float acc[1 << REG_SHIFT];       // 64 KB -> 2 blocks/CU
    unsigned t = threadIdx.x;
    unsigned r0 = blockIdx.x * NR;
    f32x4* a4 = (f32x4*)acc;

#define ADD4(E)                                                              \
    atomicAdd(&acc[(E).x >> 16], __uint_as_float((E).x << 16));              \
    atomicAdd(&acc[(E).y >> 16], __uint_as_float((E).y << 16));              \
    atomicAdd(&acc[(E).z >> 16], __uint_as_float((E).z << 16));              \
    atomicAdd(&acc[(E).w >> 16], __uint_as_float((E).w << 16));
#define KEEP4(E)                                                             \
    asm volatile("" :: "v"((E).x), "v"((E).y), "v"((E).z), "v"((E).w));

    QS q = load_q(cursor, pack, r0, t);         // prefetch region r0

#pragma unroll
    for (int k = 0; k < NR; ++k) {
        unsigned r = r0 + (unsigned)k;

        // zero this region's LDS image
#pragma unroll
        for (int i = 0; i < 4; ++i) a4[t + i * APL_T] = (f32x4)(0.f);
        asm volatile("s_waitcnt lgkmcnt(0)" ::: "memory");
        __builtin_amdgcn_s_barrier();           // zeros visible; vmcnt NOT drained

        // accumulate current region (ds_add_f32) -- ablated when !ACCUM,
        // with loaded values kept alive so the loads aren't DCE'd (rule #17).
        if (ACCUM) {
            if (t < q.nv) { ADD4(q.a) }
            if (t + APL_T < q.nv) { ADD4(q.b) }
            if ((q.nv << 2) + t < q.len) {
                atomicAdd(&acc[q.tail >> 16], __uint_as_float(q.tail << 16));
            }
        } else {
            KEEP4(q.a)
            KEEP4(q.b)
            asm volatile("" :: "v"(q.tail));
        }

        // prefetch next region BEFORE this region's store burst
        QS qn = {};
        if (k + 1 < NR) qn = load_q(cursor, pack, r + 1, t);

        asm volatile("s_waitcnt lgkmcnt(0)" ::: "memory");
        __builtin_amdgcn_s_barrier();           // all ds_adds done

        // LDS -> registers -> NT store; no vmcnt drain afterwards
        f32x4* ob = (f32x4*)(out + ((size_t)r << REG_SHIFT));
#pragma unroll
        for (int i = 0; i < 4; ++i) {
            f32x4 v = a4[t + i * APL_T];
            __builtin_nontemporal_store(v, &ob[t + i * APL_T]);
        }
        asm volatile("s_waitcnt lgkmcnt(0)" ::: "memory");  // ds_reads complete
        __builtin_amdgcn_s_barrier();           // safe to re-zero LDS next iter
        q = qn;
    }
#undef ADD4
#undef KEEP4
}

extern "C" void kernel_launch(void* const* d_in, const int* in_sizes, int n_in,
                              void* d_out, int out_size, void* d_ws, size_t ws_size,
                              hipStream_t stream) {
    float* out = (float*)d_out;

    if (ws_size >= WS_NEED) {
        unsigned* cursor = (unsigned*)d_ws;
        unsigned* pack = (unsigned*)((char*)d_ws + PACK_OFF);
        hipMemsetAsync(d_ws, 0, PACK_OFF, stream);      // zero cursors
        bin_kernel<<<NCHUNK, BIN_T, 0, stream>>>((const f32x4*)d_in[0], (const i32x4*)d_in[1],
                                                 cursor, pack);
        // MEASUREMENT: no-accum variant first (writes zeros), then the real
        // apply overwrites with correct values. dur - 156.6 = apply_noaccum.
        apply_kernel<false><<<APL_BLOCKS, APL_T, 0, stream>>>(cursor, pack, out);
        apply_kernel<true><<<APL_BLOCKS, APL_T, 0, stream>>>(cursor, pack, out);
    } else {
        hipMemsetAsync(d_out, 0, (size_t)OUT_N * sizeof(float), stream);
        int nvec = (int)(N / 4);
        unpool_scatter_kernel<<<(nvec + 255) / 256, 256, 0, stream>>>(
            (const float4*)d_in[0], (const int4*)d_in[1], out, nvec);
    }
}

// Round 20
// 156.500 us; speedup vs baseline: 1.4260x; 1.4260x over previous
//
#include <hip/hip_runtime.h>

// MaxUnpooling2D scatter-add. out flat index o = (b<<22) | (mask & ~63) | c.
// B=16 H=W=128 C=64 OH=OW=256.  N=2^24 inputs, OUT_N=2^26 outputs.
//
// FINAL (R20): restore R13, the session best (156.6us, 5.4x over naive atomics).
// Measured decomposition (R9/R12/R15/R19 ablations):
//   bin   ~50us  (counting sort; 2 LDS-atomic ops/entry — at LDS-atomic rate)
//   apply ~101us = 36 NT-store (7.1TB/s marginal = write peak, R15)
//                + 34 ds_add accumulate (R19; SQ_LDS_BANK_CONFLICT=0 -> intrinsic
//                  atomic-unit rate, not bank conflicts -> layout can't help)
//                + 31 zero/readback/loads/barriers (R13/R16/R18 attacks null)
// Structural constraint: 3 LDS-atomic ops per entry at ~1.3cyc/lane-op ≈ 84us
// across the pipeline, partially overlapping 518MB of HBM streams (~97us floor).
// Eight structural experiments failed to beat this; this is the plateau for the
// sort-then-LDS-accumulate algorithm on gfx950.

typedef float  f32x4 __attribute__((ext_vector_type(4)));
typedef int    i32x4 __attribute__((ext_vector_type(4)));
typedef unsigned int u32x4 __attribute__((ext_vector_type(4)));

constexpr long N = 1L << 24;
constexpr long OUT_N = 1L << 26;
constexpr int IN_B_SHIFT = 20;          // elements per input batch = 2^20

constexpr int REG_SHIFT = 14;           // 2^14 floats (64KB out) per region
constexpr int RPB = 256;                // regions per batch
constexpr int R = 4096;                 // total regions
constexpr unsigned CAP = 4608;          // mean 4096 + 8 sigma
constexpr int CHUNK = 8192;             // input elements per bin block
constexpr int NCHUNK = (int)(N / CHUNK);        // 2048
constexpr int BIN_T = 512;              // bin threads
constexpr int APL_T = 1024;             // apply threads
constexpr int APL_BLOCKS = 512;         // persistent apply blocks (2/CU)
constexpr int NR = R / APL_BLOCKS;      // 8 regions per apply block
constexpr int VPT = CHUNK / 4 / BIN_T;          // 4 vec4 per thread

// ws layout: u32 cursor[R] | u32 pack[R*CAP]
constexpr size_t PACK_OFF = 65536;
constexpr size_t WS_NEED = PACK_OFF + (size_t)R * CAP * 4;   // ~75.6 MB

__device__ __forceinline__ unsigned umin_(unsigned a, unsigned b) { return a < b ? a : b; }

// off14 in [0,16384), val as bf16 (RNE) in low 16 bits.
__device__ __forceinline__ unsigned pack_entry(unsigned off14, float v) {
    unsigned bu = __float_as_uint(v);
    unsigned b16 = (bu + 0x7FFFu + ((bu >> 16) & 1u)) >> 16;
    return (off14 << 16) | b16;
}

// ---------------- fallback (round-1) kernel ----------------
__global__ __launch_bounds__(256) void unpool_scatter_kernel(
    const float4* __restrict__ upd, const int4* __restrict__ mask,
    float* __restrict__ out, int nvec) {
    int i = blockIdx.x * blockDim.x + threadIdx.x;
    if (i >= nvec) return;
    float4 u = upd[i];
    int4 m = mask[i];
    int flat = i << 2;
    int b = flat >> IN_B_SHIFT;
    float* obase = out + ((long)b << 22);
    int c0 = flat & 63;
    atomicAdd(obase + ((m.x & ~63) | (c0 + 0)), u.x);
    atomicAdd(obase + ((m.y & ~63) | (c0 + 1)), u.y);
    atomicAdd(obase + ((m.z & ~63) | (c0 + 2)), u.z);
    atomicAdd(obase + ((m.w & ~63) | (c0 + 3)), u.w);
}

// -------- phase A: block-local counting sort, then coalesced queue append --------
__global__ __launch_bounds__(BIN_T, 8) void bin_kernel(
    const f32x4* __restrict__ upd, const i32x4* __restrict__ maskv,
    unsigned* __restrict__ cursor, unsigned* __restrict__ pack) {
    __shared__ unsigned       s_pack[CHUNK];    // 32 KB: packed entries (sorted)
    __shared__ unsigned char  s_reg[CHUNK];     //  8 KB: region within batch
    __shared__ unsigned s_cnt[RPB];             // histogram -> scatter cursor
    __shared__ unsigned s_lbase[RPB];           // local exclusive prefix
    __shared__ unsigned s_gbase[RPB];           // clamped global queue base
    __shared__ unsigned s_wsum[4];

    int t = threadIdx.x;
    int blk = blockIdx.x;
    if (t < RPB) s_cnt[t] = 0;
    __syncthreads();

    int vbase = blk * (CHUNK / 4);              // 2048 vec4 per block
    unsigned b = (unsigned)blk >> 7;            // 128 blocks per batch
    unsigned rbase = b << 8;

    unsigned pk[VPT][4];
    unsigned r3p[VPT];                          // 4x 8-bit region ids per vec4
#pragma unroll
    for (int g = 0; g < VPT; ++g) {
        i32x4 m = __builtin_nontemporal_load(&maskv[vbase + g * BIN_T + t]);
        f32x4 u = __builtin_nontemporal_load(&upd[vbase + g * BIN_T + t]);
        unsigned ch0 = ((unsigned)((vbase + g * BIN_T + t) << 2)) & 63u;
        unsigned rp = 0;
#define HIST(MJ, VJ, J)                                                      \
        {                                                                    \
            unsigned mm = (unsigned)(MJ), r3 = mm >> REG_SHIFT;              \
            atomicAdd(&s_cnt[r3], 1u);                                       \
            pk[g][J] = pack_entry((mm & 0x3FC0u) | (ch0 + (J)), (VJ));       \
            rp |= r3 << (8 * (J));                                           \
        }
        HIST(m.x, u.x, 0)
        HIST(m.y, u.y, 1)
        HIST(m.z, u.z, 2)
        HIST(m.w, u.w, 3)
#undef HIST
        r3p[g] = rp;
    }
    __syncthreads();

    if (t < RPB) {  // exclusive prefix scan over 256 counts + global reservation
        unsigned lane = t & 63u, wave = (unsigned)t >> 6;
        unsigned c = s_cnt[t];
        unsigned x = c;
#pragma unroll
        for (int d = 1; d < 64; d <<= 1) {
            unsigned y = __shfl_up(x, d);
            if (lane >= (unsigned)d) x += y;
        }
        if (lane == 63) s_wsum[wave] = x;
        __syncthreads();
        unsigned woff = 0;
        for (unsigned w = 0; w < wave; ++w) woff += s_wsum[w];
        unsigned excl = woff + x - c;
        s_lbase[t] = excl;
        unsigned raw = atomicAdd(&cursor[rbase + (unsigned)t], c);
        s_gbase[t] = umin_(raw, CAP);
        s_cnt[t] = excl;                        // becomes the scatter cursor
    } else {
        __syncthreads();
    }
    __syncthreads();

    // Scatter into LDS in region-sorted order.
#pragma unroll
    for (int g = 0; g < VPT; ++g) {
#pragma unroll
        for (int j = 0; j < 4; ++j) {
            unsigned r3 = (r3p[g] >> (8 * j)) & 255u;
            unsigned s = atomicAdd(&s_cnt[r3], 1u);
            s_pack[s] = pk[g][j];
            s_reg[s] = (unsigned char)r3;
        }
    }
    __syncthreads();

    // Coalesced writeback: consecutive i -> consecutive global queue slots
    // within each region run.
    for (int i = t; i < CHUNK; i += BIN_T) {
        unsigned r3 = s_reg[i];
        unsigned idx = s_gbase[r3] + ((unsigned)i - s_lbase[r3]);
        if (idx < CAP)
            pack[(size_t)(rbase + r3) * CAP + idx] = s_pack[i];
    }
}

// -------- phase B: persistent, software-pipelined (stores never drained in-loop) ----
struct QS { u32x4 a, b; unsigned tail; unsigned nv; unsigned len; };

__device__ __forceinline__ QS load_q(const unsigned* __restrict__ cursor,
                                     const unsigned* __restrict__ pack,
                                     unsigned r, unsigned t) {
    QS q;
    q.len = umin_(cursor[r], CAP);
    q.nv = q.len >> 2;
    size_t qb = (size_t)r * CAP;
    const u32x4* p4 = (const u32x4*)(pack + qb);    // CAP%4==0 -> 16B aligned
    q.a = (t < q.nv) ? __builtin_nontemporal_load(&p4[t]) : (u32x4)(0u);
    q.b = (t + APL_T < q.nv) ? __builtin_nontemporal_load(&p4[t + APL_T]) : (u32x4)(0u);
    unsigned ti = (q.nv << 2) + t;
    q.tail = (ti < q.len) ? pack[qb + ti] : 0u;
    return q;
}

__global__ __launch_bounds__(APL_T, 2) void apply_kernel(
    const unsigned* __restrict__ cursor, const unsigned* __restrict__ pack,
    float* __restrict__ out) {
    __shared__ float acc[1 << REG_SHIFT];       // 64 KB -> 2 blocks/CU
    unsigned t = threadIdx.x;
    unsigned r0 = blockIdx.x * NR;
    f32x4* a4 = (f32x4*)acc;

#define ADD4(E)                                                              \
    atomicAdd(&acc[(E).x >> 16], __uint_as_float((E).x << 16));              \
    atomicAdd(&acc[(E).y >> 16], __uint_as_float((E).y << 16));              \
    atomicAdd(&acc[(E).z >> 16], __uint_as_float((E).z << 16));              \
    atomicAdd(&acc[(E).w >> 16], __uint_as_float((E).w << 16));

    QS q = load_q(cursor, pack, r0, t);         // prefetch region r0

#pragma unroll
    for (int k = 0; k < NR; ++k) {
        unsigned r = r0 + (unsigned)k;

        // zero this region's LDS image
#pragma unroll
        for (int i = 0; i < 4; ++i) a4[t + i * APL_T] = (f32x4)(0.f);
        asm volatile("s_waitcnt lgkmcnt(0)" ::: "memory");
        __builtin_amdgcn_s_barrier();           // zeros visible; vmcnt NOT drained

        // accumulate current region from prefetched registers (ds_add_f32)
        if (t < q.nv) { ADD4(q.a) }
        if (t + APL_T < q.nv) { ADD4(q.b) }
        if ((q.nv << 2) + t < q.len) {
            atomicAdd(&acc[q.tail >> 16], __uint_as_float(q.tail << 16));
        }

        // prefetch next region BEFORE this region's store burst
        QS qn = {};
        if (k + 1 < NR) qn = load_q(cursor, pack, r + 1, t);

        asm volatile("s_waitcnt lgkmcnt(0)" ::: "memory");
        __builtin_amdgcn_s_barrier();           // all ds_adds done

        // LDS -> registers -> NT store; no vmcnt drain afterwards
        f32x4* ob = (f32x4*)(out + ((size_t)r << REG_SHIFT));
#pragma unroll
        for (int i = 0; i < 4; ++i) {
            f32x4 v = a4[t + i * APL_T];
            __builtin_nontemporal_store(v, &ob[t + i * APL_T]);
        }
        asm volatile("s_waitcnt lgkmcnt(0)" ::: "memory");  // ds_reads complete
        __builtin_amdgcn_s_barrier();           // safe to re-zero LDS next iter
        q = qn;
    }
#undef ADD4
}

extern "C" void kernel_launch(void* const* d_in, const int* in_sizes, int n_in,
                              void* d_out, int out_size, void* d_ws, size_t ws_size,
                              hipStream_t stream) {
    float* out = (float*)d_out;

    if (ws_size >= WS_NEED) {
        unsigned* cursor = (unsigned*)d_ws;
        unsigned* pack = (unsigned*)((char*)d_ws + PACK_OFF);
        hipMemsetAsync(d_ws, 0, PACK_OFF, stream);      // zero cursors
        bin_kernel<<<NCHUNK, BIN_T, 0, stream>>>((const f32x4*)d_in[0], (const i32x4*)d_in[1],
                                                 cursor, pack);
        apply_kernel<<<APL_BLOCKS, APL_T, 0, stream>>>(cursor, pack, out);
    } else {
        hipMemsetAsync(d_out, 0, (size_t)OUT_N * sizeof(float), stream);
        int nvec = (int)(N / 4);
        unpool_scatter_kernel<<<(nvec + 255) / 256, 256, 0, stream>>>(
            (const float4*)d_in[0], (const int4*)d_in[1], out, nvec);
    }
}